// Round 1
// baseline (530.084 us; speedup 1.0000x reference)
//
#include <hip/hip_runtime.h>

// Reduction: mean(|convdata[:,:,0:3,:,:] - output[:,:,0:3,:,:]|)
// Shapes: (128,100,6,32,32) f32. Sliced region = 39,321,600 elems per tensor.
// Layout: per (b,t) pair (12800 of them), 3072 contiguous floats used,
// next 3072 skipped. Vectorized as float4: 768 used / 1536 stride per pair.

#define NVEC      9830400   // 39321600 / 4
#define VEC_USED  768       // 3072 / 4
#define VEC_PITCH 1536      // 6144 / 4
#define NBLOCKS   2048
#define NTHREADS  256

__global__ __launch_bounds__(NTHREADS)
void abs_diff_partial(const float4* __restrict__ a4,
                      const float4* __restrict__ b4,
                      float* __restrict__ partials) {
    float sum = 0.0f;
    const int stride = gridDim.x * blockDim.x;
    for (int vid = blockIdx.x * blockDim.x + threadIdx.x; vid < NVEC; vid += stride) {
        int p = vid / VEC_USED;            // (b,t) pair index
        int r = vid - p * VEC_USED;        // offset within used region
        int src = p * VEC_PITCH + r;
        float4 a = a4[src];
        float4 b = b4[src];
        sum += fabsf(b.x - a.x) + fabsf(b.y - a.y)
             + fabsf(b.z - a.z) + fabsf(b.w - a.w);
    }
    // wave64 reduce
    #pragma unroll
    for (int off = 32; off > 0; off >>= 1)
        sum += __shfl_down(sum, off, 64);
    __shared__ float lds[NTHREADS / 64];
    const int wave = threadIdx.x >> 6;
    const int lane = threadIdx.x & 63;
    if (lane == 0) lds[wave] = sum;
    __syncthreads();
    if (threadIdx.x == 0) {
        float s = 0.0f;
        #pragma unroll
        for (int w = 0; w < NTHREADS / 64; ++w) s += lds[w];
        partials[blockIdx.x] = s;
    }
}

__global__ __launch_bounds__(NTHREADS)
void final_reduce(const float* __restrict__ partials,
                  float* __restrict__ out) {
    float sum = 0.0f;
    for (int i = threadIdx.x; i < NBLOCKS; i += NTHREADS)
        sum += partials[i];
    #pragma unroll
    for (int off = 32; off > 0; off >>= 1)
        sum += __shfl_down(sum, off, 64);
    __shared__ float lds[NTHREADS / 64];
    const int wave = threadIdx.x >> 6;
    const int lane = threadIdx.x & 63;
    if (lane == 0) lds[wave] = sum;
    __syncthreads();
    if (threadIdx.x == 0) {
        float s = 0.0f;
        #pragma unroll
        for (int w = 0; w < NTHREADS / 64; ++w) s += lds[w];
        out[0] = s * (1.0f / 39321600.0f);
    }
}

extern "C" void kernel_launch(void* const* d_in, const int* in_sizes, int n_in,
                              void* d_out, int out_size, void* d_ws, size_t ws_size,
                              hipStream_t stream) {
    const float4* output4   = (const float4*)d_in[0];   // "output"
    const float4* convdata4 = (const float4*)d_in[1];   // "convdata"
    float* partials = (float*)d_ws;                     // NBLOCKS floats, fully written
    float* out = (float*)d_out;

    abs_diff_partial<<<NBLOCKS, NTHREADS, 0, stream>>>(output4, convdata4, partials);
    final_reduce<<<1, NTHREADS, 0, stream>>>(partials, out);
}

// Round 2
// 526.372 us; speedup vs baseline: 1.0071x; 1.0071x over previous
//
#include <hip/hip_runtime.h>

// Reduction: mean(|convdata[:,:,0:3,:,:] - output[:,:,0:3,:,:]|)
// Shapes: (128,100,6,32,32) f32. 12800 (b,t) pairs; per pair the first
// 3*1024 = 3072 floats (12 KB) are used, next 12 KB skipped.
// Block p reads pair p: 768 float4 per tensor = 3 float4/thread @ 256 thr.

#define NPAIRS    12800
#define VEC_USED  768       // 3072 / 4
#define VEC_PITCH 1536      // 6144 / 4
#define NTHREADS  256

__global__ __launch_bounds__(NTHREADS)
void abs_diff_partial(const float4* __restrict__ a4,
                      const float4* __restrict__ b4,
                      float* __restrict__ partials) {
    const size_t base = (size_t)blockIdx.x * VEC_PITCH + threadIdx.x;

    // 3 independent load-pairs per thread — full ILP, no divides.
    float4 a0 = a4[base];
    float4 b0 = b4[base];
    float4 a1 = a4[base + NTHREADS];
    float4 b1 = b4[base + NTHREADS];
    float4 a2 = a4[base + 2 * NTHREADS];
    float4 b2 = b4[base + 2 * NTHREADS];

    float sum = fabsf(b0.x - a0.x) + fabsf(b0.y - a0.y)
              + fabsf(b0.z - a0.z) + fabsf(b0.w - a0.w)
              + fabsf(b1.x - a1.x) + fabsf(b1.y - a1.y)
              + fabsf(b1.z - a1.z) + fabsf(b1.w - a1.w)
              + fabsf(b2.x - a2.x) + fabsf(b2.y - a2.y)
              + fabsf(b2.z - a2.z) + fabsf(b2.w - a2.w);

    // wave64 reduce
    #pragma unroll
    for (int off = 32; off > 0; off >>= 1)
        sum += __shfl_down(sum, off, 64);

    __shared__ float lds[NTHREADS / 64];
    const int wave = threadIdx.x >> 6;
    const int lane = threadIdx.x & 63;
    if (lane == 0) lds[wave] = sum;
    __syncthreads();
    if (threadIdx.x == 0) {
        float s = 0.0f;
        #pragma unroll
        for (int w = 0; w < NTHREADS / 64; ++w) s += lds[w];
        partials[blockIdx.x] = s;
    }
}

#define FTHREADS 1024
__global__ __launch_bounds__(FTHREADS)
void final_reduce(const float* __restrict__ partials,
                  float* __restrict__ out) {
    float sum = 0.0f;
    for (int i = threadIdx.x; i < NPAIRS; i += FTHREADS)
        sum += partials[i];
    #pragma unroll
    for (int off = 32; off > 0; off >>= 1)
        sum += __shfl_down(sum, off, 64);
    __shared__ float lds[FTHREADS / 64];
    const int wave = threadIdx.x >> 6;
    const int lane = threadIdx.x & 63;
    if (lane == 0) lds[wave] = sum;
    __syncthreads();
    if (threadIdx.x == 0) {
        float s = 0.0f;
        #pragma unroll
        for (int w = 0; w < FTHREADS / 64; ++w) s += lds[w];
        out[0] = s * (1.0f / 39321600.0f);
    }
}

extern "C" void kernel_launch(void* const* d_in, const int* in_sizes, int n_in,
                              void* d_out, int out_size, void* d_ws, size_t ws_size,
                              hipStream_t stream) {
    const float4* output4   = (const float4*)d_in[0];   // "output"
    const float4* convdata4 = (const float4*)d_in[1];   // "convdata"
    float* partials = (float*)d_ws;                     // NPAIRS floats, fully written
    float* out = (float*)d_out;

    abs_diff_partial<<<NPAIRS, NTHREADS, 0, stream>>>(output4, convdata4, partials);
    final_reduce<<<1, FTHREADS, 0, stream>>>(partials, out);
}